// Round 14
// baseline (185.025 us; speedup 1.0000x reference)
//
#include <hip/hip_runtime.h>

// CausalSelfAttention: B=2, T=2048, DIM=1024, H=16, HD=64
// Inputs fp32; d_out fp32 = [out (B*T*DIM)] ++ [entropy (B*T)].
// Internal: bf16 MFMA, fp32 accumulation. 4 launches.
// Config: R13 base (168.2us) + QKV GEMM at 8 waves/block (same 128x128 tile,
// same LDS/grid/swizzle -> 6 waves/SIMD vs 3; the untested TLP-at-constant-
// traffic cell; mirrors attn v17's proven 256->512-thread transition).

typedef unsigned short u16;
typedef __attribute__((ext_vector_type(8))) __bf16 bf16x8;
typedef __attribute__((ext_vector_type(4))) float float4v;

#define BQ 2
#define TQ 2048
#define DIMQ 1024
#define HQ 16
#define HDQ 64

__device__ __forceinline__ float4v mfma16(bf16x8 a, bf16x8 b, float4v c) {
    return __builtin_amdgcn_mfma_f32_16x16x32_bf16(a, b, c, 0, 0, 0);
}

__device__ __forceinline__ u16 f2bf(float f) {
    unsigned x = __float_as_uint(f);
    return (u16)((x + 0x7FFFu + ((x >> 16) & 1u)) >> 16);
}

__device__ __forceinline__ uint4 cvt8(float4 a, float4 b) {
    union { uint4 v; u16 u[8]; } r;
    r.u[0] = f2bf(a.x); r.u[1] = f2bf(a.y); r.u[2] = f2bf(a.z); r.u[3] = f2bf(a.w);
    r.u[4] = f2bf(b.x); r.u[5] = f2bf(b.y); r.u[6] = f2bf(b.z); r.u[7] = f2bf(b.w);
    return r.v;
}

// async global->LDS, 16B/lane; LDS dest must be wave-uniform base + lane*16
__device__ __forceinline__ void async16(const u16* g, u16* l) {
    __builtin_amdgcn_global_load_lds(
        (const __attribute__((address_space(1))) void*)g,
        (__attribute__((address_space(3))) void*)l, 16, 0, 0);
}

// P-redistribution primitive: swap32 then swap16 on a register pair; builds
// the PV B-operand (32-key chunk) from two 16-key cvt_pk word pairs.
__device__ __forceinline__ void plswap(unsigned& a, unsigned& b) {
    asm("v_permlane32_swap_b32 %0, %1" : "+v"(a), "+v"(b));
    asm("v_permlane16_swap_b32 %0, %1" : "+v"(a), "+v"(b));
}

// ---------------------------------------------------------------------------
// transpose tile helper: in[R][C] fp32 -> out[C][R] bf16, 64x64 tile (tx,ty)
// ---------------------------------------------------------------------------
__device__ __forceinline__ void tr_tile(
    const float* __restrict__ in, u16* __restrict__ out, int R, int C,
    int tx, int ty, int tid, float (*T)[68])
{
    const int k0 = ty * 64, n0 = tx * 64;
    {
        int r = tid >> 2, cc = (tid & 3) << 4;
        const float* src = in + (size_t)(k0 + r) * C + n0 + cc;
        float4 v0 = ((const float4*)src)[0];
        float4 v1 = ((const float4*)src)[1];
        float4 v2 = ((const float4*)src)[2];
        float4 v3 = ((const float4*)src)[3];
        *(float4*)&T[r][cc + 0]  = v0;
        *(float4*)&T[r][cc + 4]  = v1;
        *(float4*)&T[r][cc + 8]  = v2;
        *(float4*)&T[r][cc + 12] = v3;
    }
    __syncthreads();
    {
        int nr = tid >> 2, kc = (tid & 3) << 4;
        union { uint4 v; u16 u[8]; } o0, o1;
#pragma unroll
        for (int j = 0; j < 8; ++j) o0.u[j] = f2bf(T[kc + j][nr]);
#pragma unroll
        for (int j = 0; j < 8; ++j) o1.u[j] = f2bf(T[kc + 8 + j][nr]);
        u16* dst = out + (size_t)(n0 + nr) * R + k0 + kc;
        ((uint4*)dst)[0] = o0.v;
        *(uint4*)(dst + 8) = o1.v;
    }
}

// ---------------------------------------------------------------------------
// fused pre-pass: [0,2048) x->bf16 ; [2048,2816) Wqkv^T ; [2816,3072) Wproj^T
// ---------------------------------------------------------------------------
__global__ __launch_bounds__(256) void prep_kernel(
    const float* __restrict__ x, const float* __restrict__ Wq,
    const float* __restrict__ Wp,
    u16* __restrict__ xb, u16* __restrict__ Wt, u16* __restrict__ Wpt)
{
    __shared__ float T[64][68];
    const int bx = blockIdx.x, tid = threadIdx.x;
    if (bx < 2048) {
        int i = (bx * 256 + tid) * 8;
        float4 a = *(const float4*)(x + i);
        float4 b = *(const float4*)(x + i + 4);
        *(uint4*)(xb + i) = cvt8(a, b);
    } else if (bx < 2816) {
        int bb = bx - 2048;
        tr_tile(Wq, Wt, DIMQ, 3 * DIMQ, bb % 48, bb / 48, tid, T);
    } else {
        int bb = bx - 2816;
        tr_tile(Wp, Wpt, DIMQ, DIMQ, bb & 15, bb >> 4, tid, T);
    }
}

// standalone Wproj^T (tight-ws fallback; runs after qkv GEMM frees Wt)
__global__ __launch_bounds__(256) void tr_cvt(
    const float* __restrict__ in, u16* __restrict__ out, int R, int C)
{
    __shared__ float T[64][68];
    tr_tile(in, out, R, C, blockIdx.x, blockIdx.y, threadIdx.x, T);
}

// ---------------------------------------------------------------------------
// QKV GEMM, 8-wave 128x128 tile: 512 threads, each wave owns 32(M)x64(N).
//  R9 counters: latency/barrier-bound (occupancy 27%, no pipe >31%).
//  This keeps tile/LDS(32KB)/grid(768=3 blocks/CU)/swizzle IDENTICAL to the
//  measured 48.7us version but doubles waves/SIMD 3->6 at only 1.5x LDS
//  fragment traffic (144 vs 96 b128/CU-iter, still ~47% of pipe) -- the
//  TLP-at-constant-traffic cell that fixed attn (v17). Staging: 512 lanes
//  cover a full 128x32 tile per async16 (srow=tid>>2 in 0..127; same XOR
//  chunk swizzle, read side unchanged since row&3 == c&3).
//  Epilogue: scatter Q(x0.125*log2e)[B,H,T,HD], K[B,H,T,HD], V^T[B,H,HD,T].
// ---------------------------------------------------------------------------
__global__ __launch_bounds__(512) void gemm_qkv8(
    const u16* __restrict__ A, const u16* __restrict__ Bt,
    u16* __restrict__ Qo, u16* __restrict__ Ko, u16* __restrict__ Vt)
{
    constexpr int K = DIMQ;             // 1024
    __shared__ u16 As[2][128 * 32];     // 2 x 8KB
    __shared__ u16 Bs[2][128 * 32];     // 2 x 8KB

    const int tid = threadIdx.x;
    // XCD swizzle over 768 blocks: XCD (flat&7) owns 96 contiguous tiles
    const int flat = blockIdx.y * 24 + blockIdx.x;
    const int swz = (flat & 7) * 96 + (flat >> 3);
    const int bm = swz / 24, bn = swz % 24;
    const int wave = tid >> 6, lane = tid & 63;
    const int quad = lane >> 4, c = lane & 15;
    const int wm = wave >> 1, wn = wave & 1;    // 4 x 2 wave grid
    const int x3 = c & 3;

    const float4v z = {0.f, 0.f, 0.f, 0.f};
    float4v acc[2][4];
#pragma unroll
    for (int mt = 0; mt < 2; ++mt)
#pragma unroll
        for (int tn = 0; tn < 4; ++tn) acc[mt][tn] = z;

    const int srow = tid >> 2;          // 0..127 (full tile rows in one call)
    const int schunk8 = (((tid & 3) ^ (srow & 3)) << 3);
    const u16* ga = A  + (size_t)(bm * 128 + srow) * K + schunk8;
    const u16* gb = Bt + (size_t)(bn * 128 + srow) * K + schunk8;

    async16(ga, As[0] + tid * 8);
    async16(gb, Bs[0] + tid * 8);

    const int niter = K >> 5;           // 32
    for (int it = 0; it < niter; ++it) {
        __syncthreads();
        if (it + 1 < niter) {
            const int nb = (it + 1) & 1;
            const int kc = (it + 1) * 32;
            async16(ga + kc, As[nb] + tid * 8);
            async16(gb + kc, Bs[nb] + tid * 8);
        }
        const u16* as = As[it & 1];
        const u16* bs = Bs[it & 1];

        bf16x8 af[2], bfr[4];
#pragma unroll
        for (int mt = 0; mt < 2; ++mt)
            af[mt] = *(const bf16x8*)&as[(wm * 32 + mt * 16 + c) * 32 +
                                         ((quad ^ x3) << 3)];
#pragma unroll
        for (int tn = 0; tn < 4; ++tn)
            bfr[tn] = *(const bf16x8*)&bs[(wn * 64 + tn * 16 + c) * 32 +
                                          ((quad ^ x3) << 3)];
#pragma unroll
        for (int mt = 0; mt < 2; ++mt)
#pragma unroll
            for (int tn = 0; tn < 4; ++tn)
                acc[mt][tn] = mfma16(af[mt], bfr[tn], acc[mt][tn]);
    }

#pragma unroll
    for (int mt = 0; mt < 2; ++mt)
#pragma unroll
        for (int tn = 0; tn < 4; ++tn) {
            int gm0 = bm * 128 + wm * 32 + mt * 16 + quad * 4;
            int gn  = bn * 128 + wn * 64 + tn * 16 + c;
            int s = gn >> 10, h = (gn >> 6) & 15, d = gn & 63;
            int b = gm0 >> 11, t0 = gm0 & 2047;
            size_t bh = (size_t)(b * HQ + h);
            if (s == 2) {
                union { unsigned long long w; u16 u[4]; } pk;
#pragma unroll
                for (int r = 0; r < 4; ++r) pk.u[r] = f2bf(acc[mt][tn][r]);
                *(unsigned long long*)&Vt[(bh * HDQ + d) * TQ + t0] = pk.w;
            } else {
                u16* dst = (s == 0) ? Qo : Ko;
                // Q scale: 1/sqrt(HD) * log2(e) -> QK^T lands in exp2 domain
                float sc = (s == 0) ? 0.18033688f : 1.0f;
#pragma unroll
                for (int r = 0; r < 4; ++r)
                    dst[(bh * TQ + t0 + r) * HDQ + d] = f2bf(acc[mt][tn][r] * sc);
            }
        }
}

// ---------------------------------------------------------------------------
// Proj GEMM (proven 2-buffer template): A[M][K] bf16, Bt[N][K] bf16, tile
// TILEM x 128, BK=32, XCD swizzle. MODE 1: fp32 store to Of; blocks bn==0,
// bm<16 also do the entropy head-average.
// ---------------------------------------------------------------------------
template <int TILEM, int MODE>
__global__ __launch_bounds__(256) void gemm_db(
    const u16* __restrict__ A, const u16* __restrict__ Bt,
    int M, int N, int K,
    u16* __restrict__ Qo, u16* __restrict__ Ko, u16* __restrict__ Vt,
    float* __restrict__ Of, const float* __restrict__ EntIn)
{
    constexpr int MT = TILEM / 32;
    constexpr int AR = TILEM / 64;
    __shared__ u16 As[2][TILEM * 32];
    __shared__ u16 Bs[2][128 * 32];

    const int tid = threadIdx.x;
    // XCD swizzle: flat id -> XCD (flat&7) owns contiguous chunk of tiles
    const int nbn = gridDim.x;
    const int flat = blockIdx.y * nbn + blockIdx.x;
    const int cpx = (nbn * gridDim.y) >> 3;
    const int swz = (flat & 7) * cpx + (flat >> 3);
    const int bm = swz / nbn, bn = swz % nbn;
    const int wave = tid >> 6, lane = tid & 63;
    const int quad = lane >> 4, c = lane & 15;
    const int wm = wave >> 1, wn = wave & 1;
    const int x3 = c & 3;

    const float4v z = {0.f, 0.f, 0.f, 0.f};
    float4v acc[MT][4];
#pragma unroll
    for (int mt = 0; mt < MT; ++mt)
#pragma unroll
        for (int tn = 0; tn < 4; ++tn) acc[mt][tn] = z;

    const int srow = tid >> 2;
    const int schunk8 = (((tid & 3) ^ (srow & 3)) << 3);
    const u16* ga = A  + (size_t)(bm * TILEM + srow) * K + schunk8;
    const u16* gb = Bt + (size_t)(bn * 128  + srow) * K + schunk8;

#pragma unroll
    for (int p = 0; p < AR; ++p)
        async16(ga + (size_t)(p * 64) * K, As[0] + p * 2048 + tid * 8);
#pragma unroll
    for (int p = 0; p < 2; ++p)
        async16(gb + (size_t)(p * 64) * K, Bs[0] + p * 2048 + tid * 8);

    const int niter = K >> 5;
    for (int it = 0; it < niter; ++it) {
        __syncthreads();
        if (it + 1 < niter) {
            const int nb = (it + 1) & 1;
            const int kc = (it + 1) * 32;
#pragma unroll
            for (int p = 0; p < AR; ++p)
                async16(ga + kc + (size_t)(p * 64) * K, As[nb] + p * 2048 + tid * 8);
#pragma unroll
            for (int p = 0; p < 2; ++p)
                async16(gb + kc + (size_t)(p * 64) * K, Bs[nb] + p * 2048 + tid * 8);
        }
        const u16* as = As[it & 1];
        const u16* bs = Bs[it & 1];

        bf16x8 af[MT], bfr[4];
#pragma unroll
        for (int mt = 0; mt < MT; ++mt)
            af[mt] = *(const bf16x8*)&as[(wm * (TILEM / 2) + mt * 16 + c) * 32 +
                                         ((quad ^ x3) << 3)];
#pragma unroll
        for (int tn = 0; tn < 4; ++tn)
            bfr[tn] = *(const bf16x8*)&bs[(wn * 64 + tn * 16 + c) * 32 +
                                          ((quad ^ x3) << 3)];
#pragma unroll
        for (int mt = 0; mt < MT; ++mt)
#pragma unroll
            for (int tn = 0; tn < 4; ++tn)
                acc[mt][tn] = mfma16(af[mt], bfr[tn], acc[mt][tn]);
    }

#pragma unroll
    for (int mt = 0; mt < MT; ++mt)
#pragma unroll
        for (int tn = 0; tn < 4; ++tn) {
            int gm0 = bm * TILEM + wm * (TILEM / 2) + mt * 16 + quad * 4;
            int gn  = bn * 128 + wn * 64 + tn * 16 + c;
            if (MODE == 0) {
                int s = gn >> 10, h = (gn >> 6) & 15, d = gn & 63;
                int b = gm0 >> 11, t0 = gm0 & 2047;
                size_t bh = (size_t)(b * HQ + h);
                if (s == 2) {
                    union { unsigned long long w; u16 u[4]; } pk;
#pragma unroll
                    for (int r = 0; r < 4; ++r) pk.u[r] = f2bf(acc[mt][tn][r]);
                    *(unsigned long long*)&Vt[(bh * HDQ + d) * TQ + t0] = pk.w;
                } else {
                    u16* dst = (s == 0) ? Qo : Ko;
                    float sc = (s == 0) ? 0.18033688f : 1.0f;
#pragma unroll
                    for (int r = 0; r < 4; ++r)
                        dst[(bh * TQ + t0 + r) * HDQ + d] = f2bf(acc[mt][tn][r] * sc);
                }
            } else {
#pragma unroll
                for (int r = 0; r < 4; ++r)
                    Of[(size_t)(gm0 + r) * N + gn] = acc[mt][tn][r];
            }
        }

    if (MODE == 1 && bn == 0 && bm < 16) {
        int i = bm * 256 + tid;
        int b = i >> 11, t = i & 2047;
        float s = 0.f;
#pragma unroll
        for (int h = 0; h < HQ; ++h) s += EntIn[((size_t)(b * HQ + h)) * TQ + t];
        Of[(size_t)BQ * TQ * DIMQ + i] = s * (1.0f / HQ);
    }
}

// ---------------------------------------------------------------------------
// Flash attention + entropy, v17 = v13 + v16 HYBRID (4 waves/SIMD at v13's
// per-CU LDS traffic). Proven round 9/13 (attn out of top-5). UNCHANGED.
// ---------------------------------------------------------------------------
__global__ __launch_bounds__(512, 4) void attn_kernel(
    const u16* __restrict__ Q, const u16* __restrict__ K,
    const u16* __restrict__ Vt, u16* __restrict__ AO,
    float* __restrict__ Ent)
{
    // d in [0,512): xcd = d&7, j = d>>3; bh = xcd*4 + (j>>4); pt = j&15,
    // flipped for j>=32 so co-resident pairs (d, d+256) sum to constant work.
    const int d = blockIdx.x;
    const int j = d >> 3;
    const int bh = (d & 7) * 4 + (j >> 4);
    int pt = j & 15;
    if (j & 32) pt = 15 - pt;
    const int qt[2] = { pt, 31 - pt };

    const int tid = threadIdx.x;
    const int wave = tid >> 6, lane = tid & 63;
    const int kw = wave & 1;                    // key half of each jt tile
    const int qh = wave >> 1;                   // q 16-row group (0..3)
    const int quad = lane >> 4, c = lane & 15;
    const int x7 = c & 7;

    // Sbuf[0..1] = K dbuf, Sbuf[2..3] = V^T dbuf (8KB each, 32KB total).
    // After the jt loop the same 32KB is reused as the cross-kw float merge
    // buffer Red[qh][32][64].
    __shared__ u16 Sbuf[4][64 * 64];
    __shared__ float lred[4][2][16], tred[4][2][16];

    const u16* Qp = Q  + (size_t)bh * TQ * HDQ;
    const u16* Kp = K  + (size_t)bh * TQ * HDQ;
    const u16* Vp = Vt + (size_t)bh * HDQ * TQ;

    const int qb[2] = { qt[0] * 64 + qh * 16, qt[1] * 64 + qh * 16 };

    // Q^T B-fragments: lane n=c -> q=qb[s]+c, d-chunks quad, quad+4
    bf16x8 qf[2][2];
#pragma unroll
    for (int s = 0; s < 2; ++s) {
        const u16* qr = Qp + (size_t)(qb[s] + c) * HDQ;
        qf[s][0] = *(const bf16x8*)(qr + quad * 8);
        qf[s][1] = *(const bf16x8*)(qr + 32 + quad * 8);
    }

    const float MX2 = 17.312336f;               // 12 * log2(e)
    const float4v z = {0.f, 0.f, 0.f, 0.f};
    const float4v mz = {-MX2, -MX2, -MX2, -MX2};
    float4v oacc[2][4];                         // [stream][tn], partial (32 keys)
#pragma unroll
    for (int s = 0; s < 2; ++s)
#pragma unroll
        for (int tn = 0; tn < 4; ++tn) oacc[s][tn] = z;
    float lp[2] = {0.f, 0.f}, tp[2] = {0.f, 0.f};

    const int ntile = qt[1] + 1;

    // staging: 512 threads cover a full 64x64 u16 tile per async16 call
    const int srow = tid >> 3;                  // 0..63
    const int schunk8 = (((tid & 7) ^ (srow & 7)) << 3);
    const u16* ka = Kp + (size_t)srow * HDQ + schunk8;
    const u16* va = Vp + (size_t)srow * TQ + schunk8;

    {
        async16(ka, Sbuf[0] + tid * 8);
        async16(va, Sbuf[2] + tid * 8);
    }

    for (int jt = 0; jt < ntile; ++jt) {
        __syncthreads();
        if (jt + 1 < ntile) {
            int nb = (jt + 1) & 1;
            async16(ka + (size_t)((jt + 1) * 64) * HDQ, Sbuf[nb] + tid * 8);
            async16(va + (jt + 1) * 64, Sbuf[2 + nb] + tid * 8);
        }
        const u16* ksb = Sbuf[jt & 1];
        const u16* vsb = Sbuf[2 + (jt & 1)];

        // This wave's 32-key half: K rows kw*32+kt*16+c (2x2 b128),
        // V^T rows tn*16+c at key-chunk kw*4+quad (4 b128). 8 b128/wave-jt.
        bf16x8 kf[2][2], vf[4];
#pragma unroll
        for (int kt = 0; kt < 2; ++kt) {
            int base = (kw * 32 + kt * 16 + c) * 64;
            kf[kt][0] = *(const bf16x8*)&ksb[base + ((quad ^ x7) << 3)];
            kf[kt][1] = *(const bf16x8*)&ksb[base + (((quad + 4) ^ x7) << 3)];
        }
#pragma unroll
        for (int tn = 0; tn < 4; ++tn)
            vf[tn] = *(const bf16x8*)&vsb[(tn * 16 + c) * 64 +
                                          (((kw * 4 + quad) ^ x7) << 3)];

#pragma unroll
        for (int s = 0; s < 2; ++s) {
            if (s == 0 && jt > qt[0]) continue;
            unsigned w0[2], w1[2];
#pragma unroll
            for (int kt = 0; kt < 2; ++kt) {
                float4v sacc = mz;
                sacc = mfma16(kf[kt][0], qf[s][0], sacc);
                sacc = mfma16(kf[kt][1], qf[s][1], sacc);
                if (jt == qt[s]) {
#pragma unroll
                    for (int r = 0; r < 4; ++r) {
                        int kg = jt * 64 + kw * 32 + kt * 16 + quad * 4 + r;
                        if (kg > qb[s] + c) sacc[r] = -1e30f;
                    }
                }
                float pv[4];
#pragma unroll
                for (int r = 0; r < 4; ++r) {
                    float sv = sacc[r];
                    float p;
                    asm("v_exp_f32 %0, %1" : "=v"(p) : "v"(sv));
                    lp[s] += p;
                    tp[s] += p * sv;
                    pv[r] = p;
                }
                asm("v_cvt_pk_bf16_f32 %0, %1, %2"
                    : "=v"(w0[kt]) : "v"(pv[0]), "v"(pv[1]));
                asm("v_cvt_pk_bf16_f32 %0, %1, %2"
                    : "=v"(w1[kt]) : "v"(pv[2]), "v"(pv[3]));
            }
            // In-register P^T B-fragment (32-key chunk, local key = quad*8)
            plswap(w0[0], w0[1]);
            plswap(w1[0], w1[1]);
            union { uint4 u; bf16x8 v; } P;
            P.u = (uint4){w0[0], w1[0], w0[1], w1[1]};
            // O^T partial (this wave's 32 keys) += V^T * P^T
            __builtin_amdgcn_s_setprio(1);
#pragma unroll
            for (int tn = 0; tn < 4; ++tn)
                oacc[s][tn] = mfma16(vf[tn], P.v, oacc[s][tn]);
            __builtin_amdgcn_s_setprio(0);
        }
    }

    // ---- merge: quads (shfl) then key-halves (LDS reuse of Sbuf) ----
#pragma unroll
    for (int s = 0; s < 2; ++s) {
        lp[s] += __shfl_xor(lp[s], 16); lp[s] += __shfl_xor(lp[s], 32);
        tp[s] += __shfl_xor(tp[s], 16); tp[s] += __shfl_xor(tp[s], 32);
    }
    __syncthreads();                 // all waves done reading Sbuf fragments

    float* Red = (float*)&Sbuf[0][0];           // [qh][32][64] floats = 32KB
    if (kw == 1) {
#pragma unroll
        for (int s = 0; s < 2; ++s) {
#pragma unroll
            for (int tn = 0; tn < 4; ++tn)
#pragma unroll
                for (int r = 0; r < 4; ++r)
                    Red[((qh * 32) + (s * 4 + tn) * 4 + r) * 64 + lane] =
                        oacc[s][tn][r];
            if (quad == 0) {
                lred[qh][s][c] = lp[s];
                tred[qh][s][c] = tp[s];
            }
        }
    }
    __syncthreads();
    if (kw == 0) {
        const int b = bh >> 4, h = bh & 15;
#pragma unroll
        for (int s = 0; s < 2; ++s) {
#pragma unroll
            for (int tn = 0; tn < 4; ++tn)
#pragma unroll
                for (int r = 0; r < 4; ++r)
                    oacc[s][tn][r] +=
                        Red[((qh * 32) + (s * 4 + tn) * 4 + r) * 64 + lane];
            float l = lp[s] + lred[qh][s][c];
            float t = tp[s] + tred[qh][s][c];

            float inv = 1.0f / l;
            u16* dst = AO + ((size_t)(b * TQ + qb[s] + c)) * DIMQ + h * HDQ;
#pragma unroll
            for (int tn = 0; tn < 4; ++tn) {
                unsigned u[4];
#pragma unroll
                for (int r = 0; r < 4; ++r)
                    u[r] = (unsigned)f2bf(oacc[s][tn][r] * inv);
                uint2 pk;
                pk.x = u[0] | (u[1] << 16);
                pk.y = u[2] | (u[3] << 16);
                *(uint2*)(dst + tn * 16 + quad * 4) = pk;
            }
            // tp in exp2-domain units: Ent = log(l) - ln2 * t/l  (MX cancels)
            if (quad == 0)
                Ent[(size_t)bh * TQ + qb[s] + c] =
                    __logf(l) - 0.69314718f * t / l;
        }
    }
}

extern "C" void kernel_launch(void* const* d_in, const int* in_sizes, int n_in,
                              void* d_out, int out_size, void* d_ws, size_t ws_size,
                              hipStream_t stream) {
    const float* x     = (const float*)d_in[0];
    const float* Wqkv  = (const float*)d_in[1];
    const float* Wproj = (const float*)d_in[2];
    float* out = (float*)d_out;

    const size_t NE = (size_t)BQ * HQ * TQ * HDQ;   // 4,194,304
    const size_t WQN = (size_t)3 * DIMQ * DIMQ;
    const size_t WPN = (size_t)DIMQ * DIMQ;
    u16* Qb  = (u16*)d_ws;
    u16* Kb  = Qb + NE;
    u16* Vtb = Kb + NE;
    u16* xb  = Vtb + NE;
    u16* Wt  = xb + NE;
    u16* AO  = xb;

    const size_t need = (4 * NE + WQN + WPN) * 2 + (size_t)BQ * HQ * TQ * 4;
    const bool room = ws_size >= need;
    u16* Wpt = room ? (Wt + WQN) : Wt;
    float* Ent = room ? (float*)(Wpt + WPN) : (float*)(Wt + WQN);

    prep_kernel<<<dim3(room ? 3072 : 2816), 256, 0, stream>>>(
        x, Wqkv, Wproj, xb, Wt, Wpt);
    gemm_qkv8<<<dim3(24, 32), 512, 0, stream>>>(xb, Wt, Qb, Kb, Vtb);
    if (!room)
        tr_cvt<<<dim3(16, 16), 256, 0, stream>>>(Wproj, Wpt, DIMQ, DIMQ);
    attn_kernel<<<dim3(512), 512, 0, stream>>>(Qb, Kb, Vtb, AO, Ent);
    gemm_db<64, 1><<<dim3(8, 64), 256, 0, stream>>>(
        AO, Wpt, BQ * TQ, DIMQ, DIMQ, nullptr, nullptr, nullptr, out, Ent);
}

// Round 15
// 167.998 us; speedup vs baseline: 1.1014x; 1.1014x over previous
//
#include <hip/hip_runtime.h>

// CausalSelfAttention: B=2, T=2048, DIM=1024, H=16, HD=64
// Inputs fp32; d_out fp32 = [out (B*T*DIM)] ++ [entropy (B*T)].
// Internal: bf16 MFMA, fp32 accumulation. 4 launches.
// FINAL = round-9/13 best-measured config (168.2-168.7us, reproduced 2x):
//   - 2-buffer 128x128 QKV GEMM, 4 waves, XCD swizzle (48.7us)
//   - attn v17: paired causal tiles, key-split 8-wave blocks (4 waves/SIMD
//     at constant LDS traffic), exp2-domain softmax, in-register P via
//     cvt_pk+permlane, PV setprio (<42us; session's main win, from 48)
//   - 64-tile proj GEMM + fused entropy head-average
// Falsified GEMM variants (full matrix): counted-vmcnt 3-buf (R10 null),
// 256x128 fat tile (R12 null, occupancy collapse), 8-wave TLP (R14
// regression, FETCH 2x from L2 thrash). Further gain requires the 8-phase
// 256^2 rewrite (T2-T5 co-designed) with multi-run race screening.

typedef unsigned short u16;
typedef __attribute__((ext_vector_type(8))) __bf16 bf16x8;
typedef __attribute__((ext_vector_type(4))) float float4v;

#define BQ 2
#define TQ 2048
#define DIMQ 1024
#define HQ 16
#define HDQ 64

__device__ __forceinline__ float4v mfma16(bf16x8 a, bf16x8 b, float4v c) {
    return __builtin_amdgcn_mfma_f32_16x16x32_bf16(a, b, c, 0, 0, 0);
}

__device__ __forceinline__ u16 f2bf(float f) {
    unsigned x = __float_as_uint(f);
    return (u16)((x + 0x7FFFu + ((x >> 16) & 1u)) >> 16);
}

__device__ __forceinline__ uint4 cvt8(float4 a, float4 b) {
    union { uint4 v; u16 u[8]; } r;
    r.u[0] = f2bf(a.x); r.u[1] = f2bf(a.y); r.u[2] = f2bf(a.z); r.u[3] = f2bf(a.w);
    r.u[4] = f2bf(b.x); r.u[5] = f2bf(b.y); r.u[6] = f2bf(b.z); r.u[7] = f2bf(b.w);
    return r.v;
}

// async global->LDS, 16B/lane; LDS dest must be wave-uniform base + lane*16
__device__ __forceinline__ void async16(const u16* g, u16* l) {
    __builtin_amdgcn_global_load_lds(
        (const __attribute__((address_space(1))) void*)g,
        (__attribute__((address_space(3))) void*)l, 16, 0, 0);
}

// P-redistribution primitive: swap32 then swap16 on a register pair; builds
// the PV B-operand (32-key chunk) from two 16-key cvt_pk word pairs.
__device__ __forceinline__ void plswap(unsigned& a, unsigned& b) {
    asm("v_permlane32_swap_b32 %0, %1" : "+v"(a), "+v"(b));
    asm("v_permlane16_swap_b32 %0, %1" : "+v"(a), "+v"(b));
}

// ---------------------------------------------------------------------------
// transpose tile helper: in[R][C] fp32 -> out[C][R] bf16, 64x64 tile (tx,ty)
// ---------------------------------------------------------------------------
__device__ __forceinline__ void tr_tile(
    const float* __restrict__ in, u16* __restrict__ out, int R, int C,
    int tx, int ty, int tid, float (*T)[68])
{
    const int k0 = ty * 64, n0 = tx * 64;
    {
        int r = tid >> 2, cc = (tid & 3) << 4;
        const float* src = in + (size_t)(k0 + r) * C + n0 + cc;
        float4 v0 = ((const float4*)src)[0];
        float4 v1 = ((const float4*)src)[1];
        float4 v2 = ((const float4*)src)[2];
        float4 v3 = ((const float4*)src)[3];
        *(float4*)&T[r][cc + 0]  = v0;
        *(float4*)&T[r][cc + 4]  = v1;
        *(float4*)&T[r][cc + 8]  = v2;
        *(float4*)&T[r][cc + 12] = v3;
    }
    __syncthreads();
    {
        int nr = tid >> 2, kc = (tid & 3) << 4;
        union { uint4 v; u16 u[8]; } o0, o1;
#pragma unroll
        for (int j = 0; j < 8; ++j) o0.u[j] = f2bf(T[kc + j][nr]);
#pragma unroll
        for (int j = 0; j < 8; ++j) o1.u[j] = f2bf(T[kc + 8 + j][nr]);
        u16* dst = out + (size_t)(n0 + nr) * R + k0 + kc;
        ((uint4*)dst)[0] = o0.v;
        *(uint4*)(dst + 8) = o1.v;
    }
}

// ---------------------------------------------------------------------------
// fused pre-pass: [0,2048) x->bf16 ; [2048,2816) Wqkv^T ; [2816,3072) Wproj^T
// ---------------------------------------------------------------------------
__global__ __launch_bounds__(256) void prep_kernel(
    const float* __restrict__ x, const float* __restrict__ Wq,
    const float* __restrict__ Wp,
    u16* __restrict__ xb, u16* __restrict__ Wt, u16* __restrict__ Wpt)
{
    __shared__ float T[64][68];
    const int bx = blockIdx.x, tid = threadIdx.x;
    if (bx < 2048) {
        int i = (bx * 256 + tid) * 8;
        float4 a = *(const float4*)(x + i);
        float4 b = *(const float4*)(x + i + 4);
        *(uint4*)(xb + i) = cvt8(a, b);
    } else if (bx < 2816) {
        int bb = bx - 2048;
        tr_tile(Wq, Wt, DIMQ, 3 * DIMQ, bb % 48, bb / 48, tid, T);
    } else {
        int bb = bx - 2816;
        tr_tile(Wp, Wpt, DIMQ, DIMQ, bb & 15, bb >> 4, tid, T);
    }
}

// standalone Wproj^T (tight-ws fallback; runs after qkv GEMM frees Wt)
__global__ __launch_bounds__(256) void tr_cvt(
    const float* __restrict__ in, u16* __restrict__ out, int R, int C)
{
    __shared__ float T[64][68];
    tr_tile(in, out, R, C, blockIdx.x, blockIdx.y, threadIdx.x, T);
}

// ---------------------------------------------------------------------------
// Double-buffered GEMM: A[M][K] bf16, Bt[N][K] bf16. Tile TILEM x 128, BK=32.
// XCD-aware block swizzle (T1): consecutive swz ids within an XCD walk bn
// fastest -> A row-panel (256KB) stays L2-local per XCD. Requires nwg%8==0.
// MODE 0: scatter -> Q(x0.125*log2e)[B,H,T,HD], K[B,H,T,HD], V^T[B,H,HD,T]
// MODE 1: fp32 store to Of; blocks bn==0,bm<16 also do entropy head-average.
// ---------------------------------------------------------------------------
template <int TILEM, int MODE>
__global__ __launch_bounds__(256) void gemm_db(
    const u16* __restrict__ A, const u16* __restrict__ Bt,
    int M, int N, int K,
    u16* __restrict__ Qo, u16* __restrict__ Ko, u16* __restrict__ Vt,
    float* __restrict__ Of, const float* __restrict__ EntIn)
{
    constexpr int MT = TILEM / 32;
    constexpr int AR = TILEM / 64;
    __shared__ u16 As[2][TILEM * 32];
    __shared__ u16 Bs[2][128 * 32];

    const int tid = threadIdx.x;
    // XCD swizzle: flat id -> XCD (flat&7) owns contiguous chunk of tiles
    const int nbn = gridDim.x;
    const int flat = blockIdx.y * nbn + blockIdx.x;
    const int cpx = (nbn * gridDim.y) >> 3;
    const int swz = (flat & 7) * cpx + (flat >> 3);
    const int bm = swz / nbn, bn = swz % nbn;
    const int wave = tid >> 6, lane = tid & 63;
    const int quad = lane >> 4, c = lane & 15;
    const int wm = wave >> 1, wn = wave & 1;
    const int x3 = c & 3;

    const float4v z = {0.f, 0.f, 0.f, 0.f};
    float4v acc[MT][4];
#pragma unroll
    for (int mt = 0; mt < MT; ++mt)
#pragma unroll
        for (int tn = 0; tn < 4; ++tn) acc[mt][tn] = z;

    const int srow = tid >> 2;
    const int schunk8 = (((tid & 3) ^ (srow & 3)) << 3);
    const u16* ga = A  + (size_t)(bm * TILEM + srow) * K + schunk8;
    const u16* gb = Bt + (size_t)(bn * 128  + srow) * K + schunk8;

#pragma unroll
    for (int p = 0; p < AR; ++p)
        async16(ga + (size_t)(p * 64) * K, As[0] + p * 2048 + tid * 8);
#pragma unroll
    for (int p = 0; p < 2; ++p)
        async16(gb + (size_t)(p * 64) * K, Bs[0] + p * 2048 + tid * 8);

    const int niter = K >> 5;
    for (int it = 0; it < niter; ++it) {
        __syncthreads();
        if (it + 1 < niter) {
            const int nb = (it + 1) & 1;
            const int kc = (it + 1) * 32;
#pragma unroll
            for (int p = 0; p < AR; ++p)
                async16(ga + kc + (size_t)(p * 64) * K, As[nb] + p * 2048 + tid * 8);
#pragma unroll
            for (int p = 0; p < 2; ++p)
                async16(gb + kc + (size_t)(p * 64) * K, Bs[nb] + p * 2048 + tid * 8);
        }
        const u16* as = As[it & 1];
        const u16* bs = Bs[it & 1];

        bf16x8 af[MT], bfr[4];
#pragma unroll
        for (int mt = 0; mt < MT; ++mt)
            af[mt] = *(const bf16x8*)&as[(wm * (TILEM / 2) + mt * 16 + c) * 32 +
                                         ((quad ^ x3) << 3)];
#pragma unroll
        for (int tn = 0; tn < 4; ++tn)
            bfr[tn] = *(const bf16x8*)&bs[(wn * 64 + tn * 16 + c) * 32 +
                                          ((quad ^ x3) << 3)];
#pragma unroll
        for (int mt = 0; mt < MT; ++mt)
#pragma unroll
            for (int tn = 0; tn < 4; ++tn)
                acc[mt][tn] = mfma16(af[mt], bfr[tn], acc[mt][tn]);
    }

#pragma unroll
    for (int mt = 0; mt < MT; ++mt)
#pragma unroll
        for (int tn = 0; tn < 4; ++tn) {
            int gm0 = bm * TILEM + wm * (TILEM / 2) + mt * 16 + quad * 4;
            int gn  = bn * 128 + wn * 64 + tn * 16 + c;
            if (MODE == 0) {
                int s = gn >> 10, h = (gn >> 6) & 15, d = gn & 63;
                int b = gm0 >> 11, t0 = gm0 & 2047;
                size_t bh = (size_t)(b * HQ + h);
                if (s == 2) {
                    union { unsigned long long w; u16 u[4]; } pk;
#pragma unroll
                    for (int r = 0; r < 4; ++r) pk.u[r] = f2bf(acc[mt][tn][r]);
                    *(unsigned long long*)&Vt[(bh * HDQ + d) * TQ + t0] = pk.w;
                } else {
                    u16* dst = (s == 0) ? Qo : Ko;
                    // Q scale: 1/sqrt(HD) * log2(e) -> QK^T lands in exp2 domain
                    float sc = (s == 0) ? 0.18033688f : 1.0f;
#pragma unroll
                    for (int r = 0; r < 4; ++r)
                        dst[(bh * TQ + t0 + r) * HDQ + d] = f2bf(acc[mt][tn][r] * sc);
                }
            } else {
#pragma unroll
                for (int r = 0; r < 4; ++r)
                    Of[(size_t)(gm0 + r) * N + gn] = acc[mt][tn][r];
            }
        }

    if (MODE == 1 && bn == 0 && bm < 16) {
        int i = bm * 256 + tid;
        int b = i >> 11, t = i & 2047;
        float s = 0.f;
#pragma unroll
        for (int h = 0; h < HQ; ++h) s += EntIn[((size_t)(b * HQ + h)) * TQ + t];
        Of[(size_t)BQ * TQ * DIMQ + i] = s * (1.0f / HQ);
    }
}

// ---------------------------------------------------------------------------
// Flash attention + entropy, v17 = v13 + v16 HYBRID (4 waves/SIMD at v13's
// per-CU LDS traffic). Proven round 9/13 (attn out of top-5).
// ---------------------------------------------------------------------------
__global__ __launch_bounds__(512, 4) void attn_kernel(
    const u16* __restrict__ Q, const u16* __restrict__ K,
    const u16* __restrict__ Vt, u16* __restrict__ AO,
    float* __restrict__ Ent)
{
    // d in [0,512): xcd = d&7, j = d>>3; bh = xcd*4 + (j>>4); pt = j&15,
    // flipped for j>=32 so co-resident pairs (d, d+256) sum to constant work.
    const int d = blockIdx.x;
    const int j = d >> 3;
    const int bh = (d & 7) * 4 + (j >> 4);
    int pt = j & 15;
    if (j & 32) pt = 15 - pt;
    const int qt[2] = { pt, 31 - pt };

    const int tid = threadIdx.x;
    const int wave = tid >> 6, lane = tid & 63;
    const int kw = wave & 1;                    // key half of each jt tile
    const int qh = wave >> 1;                   // q 16-row group (0..3)
    const int quad = lane >> 4, c = lane & 15;
    const int x7 = c & 7;

    // Sbuf[0..1] = K dbuf, Sbuf[2..3] = V^T dbuf (8KB each, 32KB total).
    // After the jt loop the same 32KB is reused as the cross-kw float merge
    // buffer Red[qh][32][64].
    __shared__ u16 Sbuf[4][64 * 64];
    __shared__ float lred[4][2][16], tred[4][2][16];

    const u16* Qp = Q  + (size_t)bh * TQ * HDQ;
    const u16* Kp = K  + (size_t)bh * TQ * HDQ;
    const u16* Vp = Vt + (size_t)bh * HDQ * TQ;

    const int qb[2] = { qt[0] * 64 + qh * 16, qt[1] * 64 + qh * 16 };

    // Q^T B-fragments: lane n=c -> q=qb[s]+c, d-chunks quad, quad+4
    bf16x8 qf[2][2];
#pragma unroll
    for (int s = 0; s < 2; ++s) {
        const u16* qr = Qp + (size_t)(qb[s] + c) * HDQ;
        qf[s][0] = *(const bf16x8*)(qr + quad * 8);
        qf[s][1] = *(const bf16x8*)(qr + 32 + quad * 8);
    }

    const float MX2 = 17.312336f;               // 12 * log2(e)
    const float4v z = {0.f, 0.f, 0.f, 0.f};
    const float4v mz = {-MX2, -MX2, -MX2, -MX2};
    float4v oacc[2][4];                         // [stream][tn], partial (32 keys)
#pragma unroll
    for (int s = 0; s < 2; ++s)
#pragma unroll
        for (int tn = 0; tn < 4; ++tn) oacc[s][tn] = z;
    float lp[2] = {0.f, 0.f}, tp[2] = {0.f, 0.f};

    const int ntile = qt[1] + 1;

    // staging: 512 threads cover a full 64x64 u16 tile per async16 call
    const int srow = tid >> 3;                  // 0..63
    const int schunk8 = (((tid & 7) ^ (srow & 7)) << 3);
    const u16* ka = Kp + (size_t)srow * HDQ + schunk8;
    const u16* va = Vp + (size_t)srow * TQ + schunk8;

    {
        async16(ka, Sbuf[0] + tid * 8);
        async16(va, Sbuf[2] + tid * 8);
    }

    for (int jt = 0; jt < ntile; ++jt) {
        __syncthreads();
        if (jt + 1 < ntile) {
            int nb = (jt + 1) & 1;
            async16(ka + (size_t)((jt + 1) * 64) * HDQ, Sbuf[nb] + tid * 8);
            async16(va + (jt + 1) * 64, Sbuf[2 + nb] + tid * 8);
        }
        const u16* ksb = Sbuf[jt & 1];
        const u16* vsb = Sbuf[2 + (jt & 1)];

        // This wave's 32-key half: K rows kw*32+kt*16+c (2x2 b128),
        // V^T rows tn*16+c at key-chunk kw*4+quad (4 b128). 8 b128/wave-jt.
        bf16x8 kf[2][2], vf[4];
#pragma unroll
        for (int kt = 0; kt < 2; ++kt) {
            int base = (kw * 32 + kt * 16 + c) * 64;
            kf[kt][0] = *(const bf16x8*)&ksb[base + ((quad ^ x7) << 3)];
            kf[kt][1] = *(const bf16x8*)&ksb[base + (((quad + 4) ^ x7) << 3)];
        }
#pragma unroll
        for (int tn = 0; tn < 4; ++tn)
            vf[tn] = *(const bf16x8*)&vsb[(tn * 16 + c) * 64 +
                                          (((kw * 4 + quad) ^ x7) << 3)];

#pragma unroll
        for (int s = 0; s < 2; ++s) {
            if (s == 0 && jt > qt[0]) continue;
            unsigned w0[2], w1[2];
#pragma unroll
            for (int kt = 0; kt < 2; ++kt) {
                float4v sacc = mz;
                sacc = mfma16(kf[kt][0], qf[s][0], sacc);
                sacc = mfma16(kf[kt][1], qf[s][1], sacc);
                if (jt == qt[s]) {
#pragma unroll
                    for (int r = 0; r < 4; ++r) {
                        int kg = jt * 64 + kw * 32 + kt * 16 + quad * 4 + r;
                        if (kg > qb[s] + c) sacc[r] = -1e30f;
                    }
                }
                float pv[4];
#pragma unroll
                for (int r = 0; r < 4; ++r) {
                    float sv = sacc[r];
                    float p;
                    asm("v_exp_f32 %0, %1" : "=v"(p) : "v"(sv));
                    lp[s] += p;
                    tp[s] += p * sv;
                    pv[r] = p;
                }
                asm("v_cvt_pk_bf16_f32 %0, %1, %2"
                    : "=v"(w0[kt]) : "v"(pv[0]), "v"(pv[1]));
                asm("v_cvt_pk_bf16_f32 %0, %1, %2"
                    : "=v"(w1[kt]) : "v"(pv[2]), "v"(pv[3]));
            }
            // In-register P^T B-fragment (32-key chunk, local key = quad*8)
            plswap(w0[0], w0[1]);
            plswap(w1[0], w1[1]);
            union { uint4 u; bf16x8 v; } P;
            P.u = (uint4){w0[0], w1[0], w0[1], w1[1]};
            // O^T partial (this wave's 32 keys) += V^T * P^T
            __builtin_amdgcn_s_setprio(1);
#pragma unroll
            for (int tn = 0; tn < 4; ++tn)
                oacc[s][tn] = mfma16(vf[tn], P.v, oacc[s][tn]);
            __builtin_amdgcn_s_setprio(0);
        }
    }

    // ---- merge: quads (shfl) then key-halves (LDS reuse of Sbuf) ----
#pragma unroll
    for (int s = 0; s < 2; ++s) {
        lp[s] += __shfl_xor(lp[s], 16); lp[s] += __shfl_xor(lp[s], 32);
        tp[s] += __shfl_xor(tp[s], 16); tp[s] += __shfl_xor(tp[s], 32);
    }
    __syncthreads();                 // all waves done reading Sbuf fragments

    float* Red = (float*)&Sbuf[0][0];           // [qh][32][64] floats = 32KB
    if (kw == 1) {
#pragma unroll
        for (int s = 0; s < 2; ++s) {
#pragma unroll
            for (int tn = 0; tn < 4; ++tn)
#pragma unroll
                for (int r = 0; r < 4; ++r)
                    Red[((qh * 32) + (s * 4 + tn) * 4 + r) * 64 + lane] =
                        oacc[s][tn][r];
            if (quad == 0) {
                lred[qh][s][c] = lp[s];
                tred[qh][s][c] = tp[s];
            }
        }
    }
    __syncthreads();
    if (kw == 0) {
        const int b = bh >> 4, h = bh & 15;
#pragma unroll
        for (int s = 0; s < 2; ++s) {
#pragma unroll
            for (int tn = 0; tn < 4; ++tn)
#pragma unroll
                for (int r = 0; r < 4; ++r)
                    oacc[s][tn][r] +=
                        Red[((qh * 32) + (s * 4 + tn) * 4 + r) * 64 + lane];
            float l = lp[s] + lred[qh][s][c];
            float t = tp[s] + tred[qh][s][c];

            float inv = 1.0f / l;
            u16* dst = AO + ((size_t)(b * TQ + qb[s] + c)) * DIMQ + h * HDQ;
#pragma unroll
            for (int tn = 0; tn < 4; ++tn) {
                unsigned u[4];
#pragma unroll
                for (int r = 0; r < 4; ++r)
                    u[r] = (unsigned)f2bf(oacc[s][tn][r] * inv);
                uint2 pk;
                pk.x = u[0] | (u[1] << 16);
                pk.y = u[2] | (u[3] << 16);
                *(uint2*)(dst + tn * 16 + quad * 4) = pk;
            }
            // tp in exp2-domain units: Ent = log(l) - ln2 * t/l  (MX cancels)
            if (quad == 0)
                Ent[(size_t)bh * TQ + qb[s] + c] =
                    __logf(l) - 0.69314718f * t / l;
        }
    }
}

extern "C" void kernel_launch(void* const* d_in, const int* in_sizes, int n_in,
                              void* d_out, int out_size, void* d_ws, size_t ws_size,
                              hipStream_t stream) {
    const float* x     = (const float*)d_in[0];
    const float* Wqkv  = (const float*)d_in[1];
    const float* Wproj = (const float*)d_in[2];
    float* out = (float*)d_out;

    const size_t NE = (size_t)BQ * HQ * TQ * HDQ;   // 4,194,304
    const size_t WQN = (size_t)3 * DIMQ * DIMQ;
    const size_t WPN = (size_t)DIMQ * DIMQ;
    u16* Qb  = (u16*)d_ws;
    u16* Kb  = Qb + NE;
    u16* Vtb = Kb + NE;
    u16* xb  = Vtb + NE;
    u16* Wt  = xb + NE;
    u16* AO  = xb;

    const size_t need = (4 * NE + WQN + WPN) * 2 + (size_t)BQ * HQ * TQ * 4;
    const bool room = ws_size >= need;
    u16* Wpt = room ? (Wt + WQN) : Wt;
    float* Ent = room ? (float*)(Wpt + WPN) : (float*)(Wt + WQN);

    prep_kernel<<<dim3(room ? 3072 : 2816), 256, 0, stream>>>(
        x, Wqkv, Wproj, xb, Wt, Wpt);
    gemm_db<128, 0><<<dim3(24, 32), 256, 0, stream>>>(
        xb, Wt, BQ * TQ, 3 * DIMQ, DIMQ, Qb, Kb, Vtb, nullptr, nullptr);
    if (!room)
        tr_cvt<<<dim3(16, 16), 256, 0, stream>>>(Wproj, Wpt, DIMQ, DIMQ);
    attn_kernel<<<dim3(512), 512, 0, stream>>>(Qb, Kb, Vtb, AO, Ent);
    gemm_db<64, 1><<<dim3(8, 64), 256, 0, stream>>>(
        AO, Wpt, BQ * TQ, DIMQ, DIMQ, nullptr, nullptr, nullptr, out, Ent);
}